// Round 10
// baseline (16091.327 us; speedup 1.0000x reference)
//
#include <hip/hip_runtime.h>
#include <math.h>

// DenseLSTMForecast: B=256, T=1024, H=128, FUTURE=32.
// R10 = R9 (MFMA pipeline) with SCALED lo-split. R9 failed absmax 2.6e-2:
// all w_lo = w - fp16(w) values (<=4.3e-5) are fp16 DENORMALS (min normal
// 6.1e-5); MFMA flushes denormal f16 inputs -> the correction term vanished,
// leaving systematic fp16 weight quantization that chaos-amplified over 1056
// steps. Fix: w_lo2 = (w - w_hi)*2^12, h_lo2 = (h - h_hi)*2^12 (both normal),
// accumulated in a SECOND accumulator: accB = w_lo2*h_hi + w_hi*h_lo2;
// gate = accA + 2^-12*accB (combined in registers). Residual ~2^-23/elem.
// Everything else identical to R9:
//   w·h = w_hi·h_hi + 2^-12(w_lo2·h_hi + w_hi·h_lo2), fp32 MFMA accumulate.
//   48 v_mfma_f32_16x16x32_f16 / wave / step; B-frags static in 128 VGPRs.
//   A[m=lane&15][k=quad*8+j], C/D[row=quad*4+reg][col=lane&15], B symmetric.
// Stages per group g (8 batch rows): s0 c1-core, s1 c2-helper, s2 c2-core,
// s3 c3-helperA, s4 c3-helperB, s5 c3-core, s6 head. 224 WGs x 512 thr;
// group's stages share an XCD (bid%8=g%8). Monotonic cached flags; payload
// via relaxed agent-scope atomics. State h stays fp32 (no compounding).

#define TSEQ 1024
#define HH   128
#define TT   1056

// ---- ws dword offsets ----
#define BWHI  0              // 6 planes x [4 kt][32 nt][64 lane][4 dw] fp16-hi
#define BWLO  196608         // same, fp16-lo2 (scaled by 2^12)
#define SCAL  393216         // xw1,xw2,xw3,bs1,bs2,bs3 (512 each)
#define WLIN  396288         // Wlin[0..384], [385]=b_lin, pad 512
#define XT    396800         // x transposed [1024][256]
#define RH1   658944         // h fp32 rings [16][256][128]
#define RH2   1183232
#define RH3   1707520
#define RO    2231808        // o ring [16][256]
#define RHL1  2235904        // packed h rings [8][32 g][16 m][128 k] u32(hi|lo2<<16)
#define RHL2  2760192
#define RP2   3284480        // partial rings [4][256][512] fp32
#define RP3A  3808768
#define RP3B  4333056
#define FLAGS 4857344        // 224 x 32-dword lines
#define WS_END 4864512
#define ZLEN  (WS_END - RH1)         // 4205568
#define PREP_T (462336 + ZLEN)       // 4667904 = 18234*256

#define RH1_64 (RH1/2)
#define RH2_64 (RH2/2)
#define RH3_64 (RH3/2)

#define LO_SCALE 4096.0f
#define LO_INV   0.000244140625f     // 2^-12

typedef unsigned long long u64;
typedef _Float16 v8h __attribute__((ext_vector_type(8)));
typedef float v4f __attribute__((ext_vector_type(4)));

__device__ __forceinline__ float sigmoidf_(float v) {
  return 1.0f / (1.0f + expf(-v));
}

__device__ __forceinline__ void wait_c(unsigned* p, unsigned tgt, unsigned& cached) {
  if (cached >= tgt) return;
  unsigned v = __hip_atomic_load(p, __ATOMIC_ACQUIRE, __HIP_MEMORY_SCOPE_AGENT);
  while (v < tgt) {
    __builtin_amdgcn_s_sleep(1);
    v = __hip_atomic_load(p, __ATOMIC_ACQUIRE, __HIP_MEMORY_SCOPE_AGENT);
  }
  cached = v;
}

// ---------------------------------------------------------------------------
__global__ void prep_kernel(const float* __restrict__ x,
                            const float* __restrict__ Wih1, const float* __restrict__ Whh1,
                            const float* __restrict__ bih1, const float* __restrict__ bhh1,
                            const float* __restrict__ Wih2, const float* __restrict__ Whh2,
                            const float* __restrict__ bih2, const float* __restrict__ bhh2,
                            const float* __restrict__ Wih3, const float* __restrict__ Whh3,
                            const float* __restrict__ bih3, const float* __restrict__ bhh3,
                            const float* __restrict__ Wlin, const float* __restrict__ blin,
                            float* __restrict__ ws) {
  int i = blockIdx.x * 256 + threadIdx.x;
  if (i < 196608) {
    // B-fragment packing: dword i -> (plane, kt, nt, lane, jd)
    int p   = i >> 15;
    int rem = i & 32767;
    int kt  = rem >> 13;
    int r2  = rem & 8191;
    int nt  = r2 >> 8;
    int r3  = r2 & 255;
    int ln  = r3 >> 2;
    int jd  = r3 & 3;
    int g = nt * 16 + (ln & 15);
    int k = kt * 32 + (ln >> 4) * 8 + jd * 2;
    float v0, v1;
    switch (p) {
      case 0:  v0 = Whh1[g * HH + k];        v1 = Whh1[g * HH + k + 1];     break;
      case 1:  v0 = Wih2[g * 129 + 1 + k];   v1 = Wih2[g * 129 + 2 + k];    break;
      case 2:  v0 = Whh2[g * HH + k];        v1 = Whh2[g * HH + k + 1];     break;
      case 3:  v0 = Wih3[g * 257 + 1 + k];   v1 = Wih3[g * 257 + 2 + k];    break;
      case 4:  v0 = Wih3[g * 257 + 129 + k]; v1 = Wih3[g * 257 + 130 + k];  break;
      default: v0 = Whh3[g * HH + k];        v1 = Whh3[g * HH + k + 1];     break;
    }
    _Float16 h0 = (_Float16)v0, h1 = (_Float16)v1;
    _Float16 l0 = (_Float16)((v0 - (float)h0) * LO_SCALE);   // scaled: normal fp16
    _Float16 l1 = (_Float16)((v1 - (float)h1) * LO_SCALE);
    unsigned hi = (unsigned)__builtin_bit_cast(unsigned short, h0)
                | ((unsigned)__builtin_bit_cast(unsigned short, h1) << 16);
    unsigned lo = (unsigned)__builtin_bit_cast(unsigned short, l0)
                | ((unsigned)__builtin_bit_cast(unsigned short, l1) << 16);
    ((unsigned*)ws)[BWHI + i] = hi;
    ((unsigned*)ws)[BWLO + i] = lo;
  } else if (i < 199680) {
    int r = i - 196608;
    float v;
    if      (r < 512)  v = Wih1[r];
    else if (r < 1024) v = Wih2[(r - 512) * 129];
    else if (r < 1536) v = Wih3[(r - 1024) * 257];
    else if (r < 2048) v = bih1[r - 1536] + bhh1[r - 1536];
    else if (r < 2560) v = bih2[r - 2048] + bhh2[r - 2048];
    else               v = bih3[r - 2560] + bhh3[r - 2560];
    ws[SCAL + r] = v;
  } else if (i < 200192) {
    int j = i - 199680;
    ws[WLIN + j] = (j < 385) ? Wlin[j] : (j == 385 ? blin[0] : 0.0f);
  } else if (i < 462336) {
    int j = i - 200192;
    int t = j >> 8, r = j & 255;
    ws[XT + j] = x[r * TSEQ + t];
  } else {
    ws[RH1 + (i - 462336)] = 0.0f;   // rings, RO, RHL, RP, flags
  }
}

// ---------------------------------------------------------------------------
// accA += Ahi*Bhi ; accB += Alo2*Bhi + Ahi*Blo2   (combine: accA + 2^-12*accB)
#define MFMA_SPLIT(ACCA, ACCB, AHI, ALO, BHI, BLO)                                     \
  ACCA = __builtin_amdgcn_mfma_f32_16x16x32_f16(AHI, __builtin_bit_cast(v8h, BHI), ACCA, 0, 0, 0); \
  ACCB = __builtin_amdgcn_mfma_f32_16x16x32_f16(ALO, __builtin_bit_cast(v8h, BHI), ACCB, 0, 0, 0); \
  ACCB = __builtin_amdgcn_mfma_f32_16x16x32_f16(AHI, __builtin_bit_cast(v8h, BLO), ACCB, 0, 0, 0);

// Core stage: gates = D(Whh*h_own) + partials + x-term + bias; activation.
template <int SSELF, int PB, int SI, int PW1, int PW2, int NP, int PR1O, int PR2O,
          int AC1, int AC2, int DRHO, int DRHLO>
__device__ void core_stage(float* __restrict__ wsm, char* SB, int g) {
  const int tid = threadIdx.x;
  const int lane = tid & 63, wv = tid >> 6;
  const int m = lane & 15, quad = lane >> 4;
  const int r0 = g * 8;

  float*    gs = (float*)SB;                 // [8][520]
  _Float16* ah = (_Float16*)(SB + 16640);    // [16][136]
  _Float16* al = (_Float16*)(SB + 20992);    // [16][136] (scaled lo2)
  float*    xs = (float*)(SB + 25344);       // [8]

  unsigned* flagb = (unsigned*)wsm + FLAGS;
  unsigned* Fself = flagb + (size_t)(SSELF * 32 + g) * 32;
  unsigned ca = 0, cb = 0, ch = 0, cc1 = 0, cc2 = 0;

  // B fragments (static)
  uint4 bhi[4][4], blo[4][4];
  #pragma unroll
  for (int kt = 0; kt < 4; ++kt)
    #pragma unroll
    for (int ntl = 0; ntl < 4; ++ntl) {
      const int di = (((PB * 4 + kt) * 32 + (wv * 4 + ntl)) * 64 + lane) * 4;
      bhi[kt][ntl] = *(const uint4*)((const unsigned*)wsm + BWHI + di);
      blo[kt][ntl] = *(const uint4*)((const unsigned*)wsm + BWLO + di);
    }
  // activation-role constants: unit u, rows row0 and row0+4
  const int row0 = tid >> 7, u = tid & 127;
  float xw4[4], bs4[4];
  #pragma unroll
  for (int q = 0; q < 4; ++q) {
    xw4[q] = wsm[SCAL + SI * 512 + q * 128 + u];
    bs4[q] = wsm[SCAL + 1536 + SI * 512 + q * 128 + u];
  }
  for (int i = tid; i < 1088; i += 512) {       // zero all 16 rows (pads too)
    ((unsigned*)ah)[i] = 0u;
    ((unsigned*)al)[i] = 0u;
  }
  float cst0 = 0.f, cst1 = 0.f;
  __syncthreads();

  for (int t = 0; t < TT; ++t) {
    if (tid == 0) {
      if constexpr (PW1 >= 0) wait_c(flagb + (size_t)(PW1 * 32 + g) * 32, (unsigned)(t + 1), ca);
      if constexpr (PW2 >= 0) wait_c(flagb + (size_t)(PW2 * 32 + g) * 32, (unsigned)(t + 1), cb);
      if constexpr (AC1 >= 0) { if (t >= 8) wait_c(flagb + (size_t)(AC1 * 32 + g) * 32, (unsigned)(t - 7), cc1); }
      if constexpr (AC2 >= 0) { if (t >= 8) wait_c(flagb + (size_t)(AC2 * 32 + g) * 32, (unsigned)(t - 7), cc2); }
      unsigned ht = (t >= 15) ? (unsigned)(t - 14) : 0u;
      if (t >= TSEQ) ht = (unsigned)t;
      if (ht) wait_c(flagb + (size_t)(6 * 32 + g) * 32, ht, ch);
    }
    __syncthreads();
    const int s16 = t & 15, s8 = t & 7, s4 = t & 3;

    if (tid < 8) {
      float xv;
      if (t < TSEQ) xv = wsm[XT + (size_t)t * 256 + r0 + tid];
      else {
        unsigned uu = __hip_atomic_load(
            (unsigned*)wsm + RO + (size_t)((t - 1) & 15) * 256 + r0 + tid,
            __ATOMIC_RELAXED, __HIP_MEMORY_SCOPE_AGENT);
        xv = __builtin_bit_cast(float, uu);
      }
      xs[tid] = xv;
    }

    // ---- MFMA: D = Whh * h_own (scaled split) ----
    v4f accA[4] = {{0,0,0,0},{0,0,0,0},{0,0,0,0},{0,0,0,0}};
    v4f accB[4] = {{0,0,0,0},{0,0,0,0},{0,0,0,0},{0,0,0,0}};
    #pragma unroll
    for (int kt = 0; kt < 4; ++kt) {
      const int k0 = kt * 32 + quad * 8;
      const v8h ahf = *(const v8h*)&ah[m * 136 + k0];
      const v8h alf = *(const v8h*)&al[m * 136 + k0];
      #pragma unroll
      for (int ntl = 0; ntl < 4; ++ntl) {
        MFMA_SPLIT(accA[ntl], accB[ntl], ahf, alf, bhi[kt][ntl], blo[kt][ntl]);
      }
    }
    if (quad < 2) {
      #pragma unroll
      for (int ntl = 0; ntl < 4; ++ntl) {
        const int c0 = (wv * 4 + ntl) * 16 + m;
        #pragma unroll
        for (int r = 0; r < 4; ++r)
          gs[(quad * 4 + r) * 520 + c0] = fmaf(LO_INV, accB[ntl][r], accA[ntl][r]);
      }
    }
    __syncthreads();

    // ---- epilogue: partials + x-term + bias; activation; publish ----
    #pragma unroll
    for (int rr = 0; rr < 2; ++rr) {
      const int row = row0 + rr * 4;
      float gv[4];
      #pragma unroll
      for (int q = 0; q < 4; ++q) gv[q] = gs[row * 520 + q * 128 + u];
      if constexpr (NP >= 1) {
        #pragma unroll
        for (int q = 0; q < 4; ++q) {
          unsigned pu = __hip_atomic_load(
              (unsigned*)wsm + PR1O + (size_t)s4 * 131072 + (size_t)(r0 + row) * 512 + q * 128 + u,
              __ATOMIC_RELAXED, __HIP_MEMORY_SCOPE_AGENT);
          gv[q] += __builtin_bit_cast(float, pu);
        }
      }
      if constexpr (NP == 2) {
        #pragma unroll
        for (int q = 0; q < 4; ++q) {
          unsigned pu = __hip_atomic_load(
              (unsigned*)wsm + PR2O + (size_t)s4 * 131072 + (size_t)(r0 + row) * 512 + q * 128 + u,
              __ATOMIC_RELAXED, __HIP_MEMORY_SCOPE_AGENT);
          gv[q] += __builtin_bit_cast(float, pu);
        }
      }
      const float xr = xs[row];
      #pragma unroll
      for (int q = 0; q < 4; ++q) gv[q] += fmaf(xw4[q], xr, bs4[q]);
      float& cref = rr ? cst1 : cst0;
      const float c = sigmoidf_(gv[1]) * cref + sigmoidf_(gv[0]) * tanhf(gv[2]);
      cref = c;
      const float h = sigmoidf_(gv[3]) * tanhf(c);
      const _Float16 hhi = (_Float16)h;
      const _Float16 hlo = (_Float16)((h - (float)hhi) * LO_SCALE);   // scaled
      ah[row * 136 + u] = hhi;
      al[row * 136 + u] = hlo;
      __hip_atomic_store(
          (unsigned*)wsm + DRHO + (size_t)s16 * 32768 + (size_t)(r0 + row) * 128 + u,
          __builtin_bit_cast(unsigned, h), __ATOMIC_RELAXED, __HIP_MEMORY_SCOPE_AGENT);
      if constexpr (DRHLO >= 0) {
        const unsigned pk = (unsigned)__builtin_bit_cast(unsigned short, hhi)
                          | ((unsigned)__builtin_bit_cast(unsigned short, hlo) << 16);
        __hip_atomic_store(
            (unsigned*)wsm + DRHLO + (size_t)s8 * 65536 + (size_t)g * 2048 + (size_t)row * 128 + u,
            pk, __ATOMIC_RELAXED, __HIP_MEMORY_SCOPE_AGENT);
      }
    }
    __syncthreads();
    if (tid == 0)
      __hip_atomic_fetch_add(Fself, 1u, __ATOMIC_RELAXED, __HIP_MEMORY_SCOPE_AGENT);
  }
}

// ---------------------------------------------------------------------------
// Helper stage: pure dot W_part * h_src(t) -> partial ring (fp32, combined).
template <int SSELF, int PB, int SRCW, int SRCO, int CONS, int DRPO>
__device__ void helper_stage(float* __restrict__ wsm, char* SB, int g) {
  const int tid = threadIdx.x;
  const int lane = tid & 63, wv = tid >> 6;
  const int m = lane & 15, quad = lane >> 4;
  const int r0 = g * 8;
  (void)SB;

  unsigned* flagb = (unsigned*)wsm + FLAGS;
  unsigned* Fself = flagb + (size_t)(SSELF * 32 + g) * 32;
  unsigned cw = 0, cc = 0;

  uint4 bhi[4][4], blo[4][4];
  #pragma unroll
  for (int kt = 0; kt < 4; ++kt)
    #pragma unroll
    for (int ntl = 0; ntl < 4; ++ntl) {
      const int di = (((PB * 4 + kt) * 32 + (wv * 4 + ntl)) * 64 + lane) * 4;
      bhi[kt][ntl] = *(const uint4*)((const unsigned*)wsm + BWHI + di);
      blo[kt][ntl] = *(const uint4*)((const unsigned*)wsm + BWLO + di);
    }
  __syncthreads();

  for (int t = 0; t < TT; ++t) {
    if (tid == 0) {
      wait_c(flagb + (size_t)(SRCW * 32 + g) * 32, (unsigned)(t + 1), cw);
      if (t >= 4) wait_c(flagb + (size_t)(CONS * 32 + g) * 32, (unsigned)(t - 3), cc);
    }
    __syncthreads();
    const int s8 = t & 7, s4 = t & 3;

    // A fragments from packed ring
    v8h Ahi[4], Alo[4];
    #pragma unroll
    for (int kt = 0; kt < 4; ++kt) {
      const int k0 = kt * 32 + quad * 8;
      const u64* p = (const u64*)((unsigned*)wsm + SRCO + (size_t)s8 * 65536
                                  + (size_t)g * 2048 + (size_t)m * 128 + k0);
      unsigned uu[8];
      #pragma unroll
      for (int q2 = 0; q2 < 4; ++q2) {
        u64 v = __hip_atomic_load(p + q2, __ATOMIC_RELAXED, __HIP_MEMORY_SCOPE_AGENT);
        uu[2 * q2]     = (unsigned)v;
        uu[2 * q2 + 1] = (unsigned)(v >> 32);
      }
      uint4 hp, lp;
      hp.x = (uu[0] & 0xffffu) | (uu[1] << 16);
      hp.y = (uu[2] & 0xffffu) | (uu[3] << 16);
      hp.z = (uu[4] & 0xffffu) | (uu[5] << 16);
      hp.w = (uu[6] & 0xffffu) | (uu[7] << 16);
      lp.x = (uu[0] >> 16) | (uu[1] & 0xffff0000u);
      lp.y = (uu[2] >> 16) | (uu[3] & 0xffff0000u);
      lp.z = (uu[4] >> 16) | (uu[5] & 0xffff0000u);
      lp.w = (uu[6] >> 16) | (uu[7] & 0xffff0000u);
      Ahi[kt] = __builtin_bit_cast(v8h, hp);
      Alo[kt] = __builtin_bit_cast(v8h, lp);
    }

    v4f accA[4] = {{0,0,0,0},{0,0,0,0},{0,0,0,0},{0,0,0,0}};
    v4f accB[4] = {{0,0,0,0},{0,0,0,0},{0,0,0,0},{0,0,0,0}};
    #pragma unroll
    for (int kt = 0; kt < 4; ++kt)
      #pragma unroll
      for (int ntl = 0; ntl < 4; ++ntl) {
        MFMA_SPLIT(accA[ntl], accB[ntl], Ahi[kt], Alo[kt], bhi[kt][ntl], blo[kt][ntl]);
      }

    if (quad < 2) {
      #pragma unroll
      for (int ntl = 0; ntl < 4; ++ntl) {
        const int c0 = (wv * 4 + ntl) * 16 + m;
        #pragma unroll
        for (int r = 0; r < 4; ++r) {
          const float pv = fmaf(LO_INV, accB[ntl][r], accA[ntl][r]);
          __hip_atomic_store(
              (unsigned*)wsm + DRPO + (size_t)s4 * 131072 + (size_t)(r0 + quad * 4 + r) * 512 + c0,
              __builtin_bit_cast(unsigned, pv),
              __ATOMIC_RELAXED, __HIP_MEMORY_SCOPE_AGENT);
        }
      }
    }
    __syncthreads();
    if (tid == 0)
      __hip_atomic_fetch_add(Fself, 1u, __ATOMIC_RELAXED, __HIP_MEMORY_SCOPE_AGENT);
  }
}

// ---------------------------------------------------------------------------
__device__ void head_stage(float* __restrict__ wsm, char* SB, int g,
                           float* __restrict__ out) {
  const int tid = threadIdx.x;
  const int r0 = g * 8;
  float* wl   = (float*)SB;                 // [512]
  float* hin  = (float*)(SB + 2048);        // [3][8][128]
  float* obuf = (float*)(SB + 14336);       // [8][32]
  float* xv   = (float*)(SB + 15360);       // [8]

  u64* ws64 = (u64*)wsm;
  unsigned* flagb = (unsigned*)wsm + FLAGS;
  unsigned* Fself = flagb + (size_t)(6 * 32 + g) * 32;
  unsigned* Fc3   = flagb + (size_t)(5 * 32 + g) * 32;
  unsigned c3c = 0;

  wl[tid] = wsm[WLIN + tid];
  if (tid < 8) xv[tid] = wsm[XT + r0 + tid];
  __syncthreads();

  const int row = tid >> 6, lane = tid & 63;

  for (int t = 0; t < TT; ++t) {
    if (tid == 0) wait_c(Fc3, (unsigned)(t + 1), c3c);
    __syncthreads();
    const int slot = t & 15;

    for (int i = tid; i < 1536; i += 512) {
      const int s = i >> 9, rem = i & 511;
      const int a = rem >> 6, up = rem & 63;
      const size_t base = (s == 0) ? (size_t)RH1_64 : (s == 1) ? (size_t)RH2_64 : (size_t)RH3_64;
      u64 v = __hip_atomic_load(
          ws64 + base + (size_t)slot * 16384 + (size_t)(r0 + a) * 64 + up,
          __ATOMIC_RELAXED, __HIP_MEMORY_SCOPE_AGENT);
      *(u64*)&hin[(s * 8 + a) * HH + up * 2] = v;
    }
    __syncthreads();

    float s = 0.f;
    #pragma unroll
    for (int q = 0; q < 6; ++q) {
      const int j = lane + 64 * q;
      const int si = j >> 7, uu = j & 127;
      s = fmaf(wl[1 + j], hin[(si * 8 + row) * HH + uu], s);
    }
    #pragma unroll
    for (int off = 32; off > 0; off >>= 1) s += __shfl_down(s, off, 64);
    if (lane == 0) {
      const float o = s + fmaf(wl[0], xv[row], wl[385]);
      obuf[row * 32 + (t & 31)] = o;
      __hip_atomic_store((unsigned*)wsm + RO + (size_t)slot * 256 + r0 + row,
                         __builtin_bit_cast(unsigned, o),
                         __ATOMIC_RELAXED, __HIP_MEMORY_SCOPE_AGENT);
      xv[row] = (t + 1 < TSEQ) ? wsm[XT + (size_t)(t + 1) * 256 + r0 + row] : o;
    }
    __syncthreads();
    if (tid == 0)
      __hip_atomic_fetch_add(Fself, 1u, __ATOMIC_RELAXED, __HIP_MEMORY_SCOPE_AGENT);

    if ((t & 31) == 31) {
      const int tb = t - 31;
      if (tid < 256) {
        const int a = tid >> 5, mm = tid & 31;
        out[(size_t)(r0 + a) * TT + tb + mm] = obuf[a * 32 + mm];
      }
    }
  }
}

// ---------------------------------------------------------------------------
__global__ __launch_bounds__(512, 2)
void lstm_kernel(float* __restrict__ wsm, float* __restrict__ out) {
  __shared__ __align__(16) char SB[25600];
  const int s = blockIdx.x >> 5, g = blockIdx.x & 31;
  switch (s) {
    case 0: core_stage<0, 0, 0, -1, -1, 0, 0, 0, 1, 3, RH1, RHL1>(wsm, SB, g); break;
    case 1: helper_stage<1, 1, 0, RHL1, 2, RP2>(wsm, SB, g); break;
    case 2: core_stage<2, 2, 1, 1, -1, 1, RP2, 0, 4, -1, RH2, RHL2>(wsm, SB, g); break;
    case 3: helper_stage<3, 3, 0, RHL1, 5, RP3A>(wsm, SB, g); break;
    case 4: helper_stage<4, 4, 2, RHL2, 5, RP3B>(wsm, SB, g); break;
    case 5: core_stage<5, 5, 2, 3, 4, 2, RP3A, RP3B, -1, -1, RH3, -1>(wsm, SB, g); break;
    default: head_stage(wsm, SB, g, out); break;
  }
}

// ---------------------------------------------------------------------------
extern "C" void kernel_launch(void* const* d_in, const int* in_sizes, int n_in,
                              void* d_out, int out_size, void* d_ws, size_t ws_size,
                              hipStream_t stream) {
  const float* x    = (const float*)d_in[0];
  const float* Wih1 = (const float*)d_in[1];
  const float* Whh1 = (const float*)d_in[2];
  const float* bih1 = (const float*)d_in[3];
  const float* bhh1 = (const float*)d_in[4];
  const float* Wih2 = (const float*)d_in[5];
  const float* Whh2 = (const float*)d_in[6];
  const float* bih2 = (const float*)d_in[7];
  const float* bhh2 = (const float*)d_in[8];
  const float* Wih3 = (const float*)d_in[9];
  const float* Whh3 = (const float*)d_in[10];
  const float* bih3 = (const float*)d_in[11];
  const float* bhh3 = (const float*)d_in[12];
  const float* Wlin = (const float*)d_in[13];
  const float* blin = (const float*)d_in[14];
  float* ws  = (float*)d_ws;
  float* out = (float*)d_out;

  prep_kernel<<<PREP_T / 256, 256, 0, stream>>>(
      x, Wih1, Whh1, bih1, bhh1, Wih2, Whh2, bih2, bhh2,
      Wih3, Whh3, bih3, bhh3, Wlin, blin, ws);
  lstm_kernel<<<224, 512, 0, stream>>>(ws, out);
}

// Round 12
// 11278.464 us; speedup vs baseline: 1.4267x; 1.4267x over previous
//
#include <hip/hip_runtime.h>
#include <math.h>

// DenseLSTMForecast: B=256, T=1024, H=128, FUTURE=32.
// R12 = R11 with the MFMA_SPLIT macro wrapped in do{}while(0) (R11 failed to
// compile: 3-statement macro as unbraced loop body -> 'ntl' out of scope).
// R11 design: 3-WG-per-group MFMA pipeline (collapsed from R10's 7).
// R10 post-mortem: numerics fixed (absmax = bf16 floor 4.88e-4) but 16 ms with
// MfmaUtil 3.3% / VALUBusy 4.2% -> sync-latency bound: 7 WGs/group with
// depth-4 partial rings = small-slack flag cycles; MFMA shrank work to 0.3us
// so RTTs dominate. R11/R12: 3 WGs/group, 2 weight planes each (256 VGPRs),
// ALL rings depth>=8, anti-deps via cached flags (1 poll per ~8 steps).
// One forward hop per stage per step -> steady-state throughput = stage time.
//   W1: c1-core (Whh1) + p2 = Wih2h*h1      -> RH1P (packed h1) + RP2
//   W2: c2-core (Whh2) + pA = Wih3a*h1      -> RH2P (packed h2) + RPA
//   W3: pB = Wih3b*h2 + c3-core (Whh3) + head -> RO, out, FH
// 96 WGs x 512 thr; group's WGs share an XCD (bid%8 = g%8).
// Numerics identical to R10: w*h = w_hi*h_hi + 2^-12(w_lo2*h_hi + w_hi*h_lo2),
// fp32 MFMA accumulate, fp32 state. Packed h ring: u32 = hi | lo2<<16.

#define TSEQ 1024
#define HH   128
#define TT   1056

// ---- ws dword offsets ----
#define BWHI  0              // 6 planes x [4 kt][32 nt][64 lane][4 dw] fp16-hi
#define BWLO  196608         // same, fp16-lo2 (scaled 2^12)
#define SCAL  393216         // xw1,xw2,xw3,bs1,bs2,bs3 (512 each)
#define WLIN  396288         // Wlin[0..384], [385]=b_lin, pad 512
#define XT    396800         // x transposed [1024][256]
#define RH1P  658944         // packed h1 ring [8][256][128] u32
#define RH2P  921088         // packed h2 ring [8][256][128] u32
#define RP2   1183232        // p2 ring [8][256][512] fp32
#define RPA   2231808        // pA ring [8][256][512] fp32
#define RO    3280384        // o ring [16][256] fp32
#define FLAGS 3284480        // 96 x 32-dword lines
#define WS_END 3287552
#define ZLEN  (WS_END - RH1P)        // 2628608
#define PREP_T (462336 + ZLEN)       // 3090944 = 12074*256

#define LO_SCALE 4096.0f
#define LO_INV   0.000244140625f     // 2^-12

typedef unsigned long long u64;
typedef _Float16 v8h __attribute__((ext_vector_type(8)));
typedef float v4f __attribute__((ext_vector_type(4)));

__device__ __forceinline__ float sigmoidf_(float v) {
  return 1.0f / (1.0f + expf(-v));
}

__device__ __forceinline__ void wait_c(unsigned* p, unsigned tgt, unsigned& cached) {
  if (cached >= tgt) return;
  unsigned v = __hip_atomic_load(p, __ATOMIC_ACQUIRE, __HIP_MEMORY_SCOPE_AGENT);
  while (v < tgt) {
    __builtin_amdgcn_s_sleep(1);
    v = __hip_atomic_load(p, __ATOMIC_ACQUIRE, __HIP_MEMORY_SCOPE_AGENT);
  }
  cached = v;
}

// ---------------------------------------------------------------------------
__global__ void prep_kernel(const float* __restrict__ x,
                            const float* __restrict__ Wih1, const float* __restrict__ Whh1,
                            const float* __restrict__ bih1, const float* __restrict__ bhh1,
                            const float* __restrict__ Wih2, const float* __restrict__ Whh2,
                            const float* __restrict__ bih2, const float* __restrict__ bhh2,
                            const float* __restrict__ Wih3, const float* __restrict__ Whh3,
                            const float* __restrict__ bih3, const float* __restrict__ bhh3,
                            const float* __restrict__ Wlin, const float* __restrict__ blin,
                            float* __restrict__ ws) {
  int i = blockIdx.x * 256 + threadIdx.x;
  if (i < 196608) {
    // B-fragment packing (layout verified by R10): dword i -> (plane,kt,nt,lane,jd)
    int p   = i >> 15;
    int rem = i & 32767;
    int kt  = rem >> 13;
    int r2  = rem & 8191;
    int nt  = r2 >> 8;
    int r3  = r2 & 255;
    int ln  = r3 >> 2;
    int jd  = r3 & 3;
    int g = nt * 16 + (ln & 15);
    int k = kt * 32 + (ln >> 4) * 8 + jd * 2;
    float v0, v1;
    switch (p) {
      case 0:  v0 = Whh1[g * HH + k];        v1 = Whh1[g * HH + k + 1];     break;
      case 1:  v0 = Wih2[g * 129 + 1 + k];   v1 = Wih2[g * 129 + 2 + k];    break;
      case 2:  v0 = Whh2[g * HH + k];        v1 = Whh2[g * HH + k + 1];     break;
      case 3:  v0 = Wih3[g * 257 + 1 + k];   v1 = Wih3[g * 257 + 2 + k];    break;
      case 4:  v0 = Wih3[g * 257 + 129 + k]; v1 = Wih3[g * 257 + 130 + k];  break;
      default: v0 = Whh3[g * HH + k];        v1 = Whh3[g * HH + k + 1];     break;
    }
    _Float16 h0 = (_Float16)v0, h1 = (_Float16)v1;
    _Float16 l0 = (_Float16)((v0 - (float)h0) * LO_SCALE);
    _Float16 l1 = (_Float16)((v1 - (float)h1) * LO_SCALE);
    unsigned hi = (unsigned)__builtin_bit_cast(unsigned short, h0)
                | ((unsigned)__builtin_bit_cast(unsigned short, h1) << 16);
    unsigned lo = (unsigned)__builtin_bit_cast(unsigned short, l0)
                | ((unsigned)__builtin_bit_cast(unsigned short, l1) << 16);
    ((unsigned*)ws)[BWHI + i] = hi;
    ((unsigned*)ws)[BWLO + i] = lo;
  } else if (i < 199680) {
    int r = i - 196608;
    float v;
    if      (r < 512)  v = Wih1[r];
    else if (r < 1024) v = Wih2[(r - 512) * 129];
    else if (r < 1536) v = Wih3[(r - 1024) * 257];
    else if (r < 2048) v = bih1[r - 1536] + bhh1[r - 1536];
    else if (r < 2560) v = bih2[r - 2048] + bhh2[r - 2048];
    else               v = bih3[r - 2560] + bhh3[r - 2560];
    ws[SCAL + r] = v;
  } else if (i < 200192) {
    int j = i - 199680;
    ws[WLIN + j] = (j < 385) ? Wlin[j] : (j == 385 ? blin[0] : 0.0f);
  } else if (i < 462336) {
    int j = i - 200192;
    int t = j >> 8, r = j & 255;
    ws[XT + j] = x[r * TSEQ + t];
  } else {
    ws[RH1P + (i - 462336)] = 0.0f;  // rings, RO, flags (ws is 0xAA-poisoned)
  }
}

// ---------------------------------------------------------------------------
#define MFMA_SPLIT(ACCA, ACCB, AHI, ALO, BHI, BLO) do {                                \
  ACCA = __builtin_amdgcn_mfma_f32_16x16x32_f16(AHI, __builtin_bit_cast(v8h, BHI), ACCA, 0, 0, 0); \
  ACCB = __builtin_amdgcn_mfma_f32_16x16x32_f16(ALO, __builtin_bit_cast(v8h, BHI), ACCB, 0, 0, 0); \
  ACCB = __builtin_amdgcn_mfma_f32_16x16x32_f16(AHI, __builtin_bit_cast(v8h, BLO), ACCB, 0, 0, 0); \
} while (0)

#define ZACC4(A) do { A[0] = (v4f){0,0,0,0}; A[1] = (v4f){0,0,0,0}; \
                      A[2] = (v4f){0,0,0,0}; A[3] = (v4f){0,0,0,0}; } while (0)

// ---------------------------------------------------------------------------
// W1: c1-core + p2 helper. Planes 0 (Whh1), 1 (Wih2h).
__device__ void stage_w1(float* __restrict__ wsm, char* SB, int g) {
  const int tid = threadIdx.x;
  const int lane = tid & 63, wv = tid >> 6;
  const int m = lane & 15, quad = lane >> 4;
  const int r0 = g * 8;

  float*    gs  = (float*)SB;                 // [8][520]
  _Float16* ah1 = (_Float16*)(SB + 16640);    // [16][136]
  _Float16* al1 = (_Float16*)(SB + 20992);
  float*    xs  = (float*)(SB + 25344);       // [8]

  unsigned* flagb = (unsigned*)wsm + FLAGS;
  unsigned* FW1 = flagb + (size_t)(0 * 32 + g) * 32;
  unsigned* FW2 = flagb + (size_t)(1 * 32 + g) * 32;
  unsigned* FH  = flagb + (size_t)(2 * 32 + g) * 32;
  unsigned cw2 = 0, chh = 0;

  uint4 bhi[2][4][4], blo[2][4][4];
  #pragma unroll
  for (int p = 0; p < 2; ++p)
    #pragma unroll
    for (int kt = 0; kt < 4; ++kt)
      #pragma unroll
      for (int ntl = 0; ntl < 4; ++ntl) {
        const int di = (((p * 4 + kt) * 32 + (wv * 4 + ntl)) * 64 + lane) * 4;
        bhi[p][kt][ntl] = *(const uint4*)((const unsigned*)wsm + BWHI + di);
        blo[p][kt][ntl] = *(const uint4*)((const unsigned*)wsm + BWLO + di);
      }
  const int row0 = tid >> 7, u = tid & 127;
  float xw4[4], bs4[4];
  #pragma unroll
  for (int q = 0; q < 4; ++q) {
    xw4[q] = wsm[SCAL + 0 * 512 + q * 128 + u];
    bs4[q] = wsm[SCAL + 1536 + 0 * 512 + q * 128 + u];
  }
  for (int i = tid; i < 1088; i += 512) {
    ((unsigned*)ah1)[i] = 0u;
    ((unsigned*)al1)[i] = 0u;
  }
  float cst0 = 0.f, cst1 = 0.f;
  __syncthreads();

  for (int t = 0; t < TT; ++t) {
    if (tid == 0) {
      if (t >= 8) {
        wait_c(FW2, (unsigned)(t - 7), cw2);
        wait_c(FH,  (unsigned)(t - 7), chh);
      }
      if (t >= TSEQ) wait_c(FH, (unsigned)t, chh);
    }
    __syncthreads();
    const int s8 = t & 7;

    if (tid < 8) {
      float xv;
      if (t < TSEQ) xv = wsm[XT + (size_t)t * 256 + r0 + tid];
      else {
        unsigned uu = __hip_atomic_load(
            (unsigned*)wsm + RO + (size_t)((t - 1) & 15) * 256 + r0 + tid,
            __ATOMIC_RELAXED, __HIP_MEMORY_SCOPE_AGENT);
        xv = __builtin_bit_cast(float, uu);
      }
      xs[tid] = xv;
    }

    // ---- c1 MFMA: Whh1 * h1own ----
    v4f accA[4], accB[4];
    ZACC4(accA); ZACC4(accB);
    #pragma unroll
    for (int kt = 0; kt < 4; ++kt) {
      const int k0 = kt * 32 + quad * 8;
      const v8h ahf = *(const v8h*)&ah1[m * 136 + k0];
      const v8h alf = *(const v8h*)&al1[m * 136 + k0];
      #pragma unroll
      for (int ntl = 0; ntl < 4; ++ntl) {
        MFMA_SPLIT(accA[ntl], accB[ntl], ahf, alf, bhi[0][kt][ntl], blo[0][kt][ntl]);
      }
    }
    if (quad < 2) {
      #pragma unroll
      for (int ntl = 0; ntl < 4; ++ntl) {
        const int c0 = (wv * 4 + ntl) * 16 + m;
        #pragma unroll
        for (int r = 0; r < 4; ++r)
          gs[(quad * 4 + r) * 520 + c0] = fmaf(LO_INV, accB[ntl][r], accA[ntl][r]);
      }
    }
    __syncthreads();

    // ---- epi1: activation, h1 -> LDS + packed ring ----
    #pragma unroll
    for (int rr = 0; rr < 2; ++rr) {
      const int row = row0 + rr * 4;
      float gv[4];
      #pragma unroll
      for (int q = 0; q < 4; ++q) gv[q] = gs[row * 520 + q * 128 + u];
      const float xr = xs[row];
      #pragma unroll
      for (int q = 0; q < 4; ++q) gv[q] += fmaf(xw4[q], xr, bs4[q]);
      float& cref = rr ? cst1 : cst0;
      const float c = sigmoidf_(gv[1]) * cref + sigmoidf_(gv[0]) * tanhf(gv[2]);
      cref = c;
      const float h = sigmoidf_(gv[3]) * tanhf(c);
      const _Float16 hhi = (_Float16)h;
      const _Float16 hlo = (_Float16)((h - (float)hhi) * LO_SCALE);
      ah1[row * 136 + u] = hhi;
      al1[row * 136 + u] = hlo;
      const unsigned pk = (unsigned)__builtin_bit_cast(unsigned short, hhi)
                        | ((unsigned)__builtin_bit_cast(unsigned short, hlo) << 16);
      __hip_atomic_store(
          (unsigned*)wsm + RH1P + (size_t)s8 * 32768 + (size_t)(r0 + row) * 128 + u,
          pk, __ATOMIC_RELAXED, __HIP_MEMORY_SCOPE_AGENT);
    }
    __syncthreads();

    // ---- p2 MFMA: Wih2h * h1(t) -> RP2 ----
    ZACC4(accA); ZACC4(accB);
    #pragma unroll
    for (int kt = 0; kt < 4; ++kt) {
      const int k0 = kt * 32 + quad * 8;
      const v8h ahf = *(const v8h*)&ah1[m * 136 + k0];
      const v8h alf = *(const v8h*)&al1[m * 136 + k0];
      #pragma unroll
      for (int ntl = 0; ntl < 4; ++ntl) {
        MFMA_SPLIT(accA[ntl], accB[ntl], ahf, alf, bhi[1][kt][ntl], blo[1][kt][ntl]);
      }
    }
    if (quad < 2) {
      #pragma unroll
      for (int ntl = 0; ntl < 4; ++ntl) {
        const int c0 = (wv * 4 + ntl) * 16 + m;
        #pragma unroll
        for (int r = 0; r < 4; ++r) {
          const float pv = fmaf(LO_INV, accB[ntl][r], accA[ntl][r]);
          __hip_atomic_store(
              (unsigned*)wsm + RP2 + (size_t)s8 * 131072 + (size_t)(r0 + quad * 4 + r) * 512 + c0,
              __builtin_bit_cast(unsigned, pv),
              __ATOMIC_RELAXED, __HIP_MEMORY_SCOPE_AGENT);
        }
      }
    }
    __syncthreads();
    if (tid == 0)
      __hip_atomic_fetch_add(FW1, 1u, __ATOMIC_RELAXED, __HIP_MEMORY_SCOPE_AGENT);
  }
}

// ---------------------------------------------------------------------------
// W2: c2-core + pA helper. Planes 2 (Whh2), 3 (Wih3a).
__device__ void stage_w2(float* __restrict__ wsm, char* SB, int g) {
  const int tid = threadIdx.x;
  const int lane = tid & 63, wv = tid >> 6;
  const int m = lane & 15, quad = lane >> 4;
  const int r0 = g * 8;

  float*    gs   = (float*)SB;
  _Float16* ah2  = (_Float16*)(SB + 16640);
  _Float16* al2  = (_Float16*)(SB + 20992);
  _Float16* ah1i = (_Float16*)(SB + 25344);
  _Float16* al1i = (_Float16*)(SB + 29696);
  float*    xs   = (float*)(SB + 34048);

  unsigned* flagb = (unsigned*)wsm + FLAGS;
  unsigned* FW1 = flagb + (size_t)(0 * 32 + g) * 32;
  unsigned* FW2 = flagb + (size_t)(1 * 32 + g) * 32;
  unsigned* FH  = flagb + (size_t)(2 * 32 + g) * 32;
  unsigned cw1 = 0, chh = 0;

  uint4 bhi[2][4][4], blo[2][4][4];
  #pragma unroll
  for (int p = 0; p < 2; ++p)
    #pragma unroll
    for (int kt = 0; kt < 4; ++kt)
      #pragma unroll
      for (int ntl = 0; ntl < 4; ++ntl) {
        const int di = ((((2 + p) * 4 + kt) * 32 + (wv * 4 + ntl)) * 64 + lane) * 4;
        bhi[p][kt][ntl] = *(const uint4*)((const unsigned*)wsm + BWHI + di);
        blo[p][kt][ntl] = *(const uint4*)((const unsigned*)wsm + BWLO + di);
      }
  const int row0 = tid >> 7, u = tid & 127;
  float xw4[4], bs4[4];
  #pragma unroll
  for (int q = 0; q < 4; ++q) {
    xw4[q] = wsm[SCAL + 1 * 512 + q * 128 + u];
    bs4[q] = wsm[SCAL + 1536 + 1 * 512 + q * 128 + u];
  }
  for (int i = tid; i < 1088; i += 512) {
    ((unsigned*)ah2)[i] = 0u;  ((unsigned*)al2)[i] = 0u;
    ((unsigned*)ah1i)[i] = 0u; ((unsigned*)al1i)[i] = 0u;
  }
  float cst0 = 0.f, cst1 = 0.f;
  __syncthreads();

  for (int t = 0; t < TT; ++t) {
    if (tid == 0) {
      wait_c(FW1, (unsigned)(t + 1), cw1);
      if (t >= 8) wait_c(FH, (unsigned)(t - 7), chh);
      if (t >= TSEQ) wait_c(FH, (unsigned)t, chh);
    }
    __syncthreads();
    const int s8 = t & 7;

    // stage packed h1(t)
    for (int i = tid; i < 1024; i += 512) {
      const int row = i >> 7, uu = i & 127;
      unsigned v = __hip_atomic_load(
          (unsigned*)wsm + RH1P + (size_t)s8 * 32768 + (size_t)(r0 + row) * 128 + uu,
          __ATOMIC_RELAXED, __HIP_MEMORY_SCOPE_AGENT);
      ah1i[row * 136 + uu] = __builtin_bit_cast(_Float16, (unsigned short)(v & 0xffffu));
      al1i[row * 136 + uu] = __builtin_bit_cast(_Float16, (unsigned short)(v >> 16));
    }
    if (tid < 8) {
      float xv;
      if (t < TSEQ) xv = wsm[XT + (size_t)t * 256 + r0 + tid];
      else {
        unsigned uu = __hip_atomic_load(
            (unsigned*)wsm + RO + (size_t)((t - 1) & 15) * 256 + r0 + tid,
            __ATOMIC_RELAXED, __HIP_MEMORY_SCOPE_AGENT);
        xv = __builtin_bit_cast(float, uu);
      }
      xs[tid] = xv;
    }
    __syncthreads();

    // ---- c2 MFMA: Whh2 * h2own ----
    v4f accA[4], accB[4];
    ZACC4(accA); ZACC4(accB);
    #pragma unroll
    for (int kt = 0; kt < 4; ++kt) {
      const int k0 = kt * 32 + quad * 8;
      const v8h ahf = *(const v8h*)&ah2[m * 136 + k0];
      const v8h alf = *(const v8h*)&al2[m * 136 + k0];
      #pragma unroll
      for (int ntl = 0; ntl < 4; ++ntl) {
        MFMA_SPLIT(accA[ntl], accB[ntl], ahf, alf, bhi[0][kt][ntl], blo[0][kt][ntl]);
      }
    }
    if (quad < 2) {
      #pragma unroll
      for (int ntl = 0; ntl < 4; ++ntl) {
        const int c0 = (wv * 4 + ntl) * 16 + m;
        #pragma unroll
        for (int r = 0; r < 4; ++r)
          gs[(quad * 4 + r) * 520 + c0] = fmaf(LO_INV, accB[ntl][r], accA[ntl][r]);
      }
    }
    __syncthreads();

    // ---- epi2: + p2 ring + x-term; h2 -> LDS + packed ring ----
    #pragma unroll
    for (int rr = 0; rr < 2; ++rr) {
      const int row = row0 + rr * 4;
      float gv[4];
      #pragma unroll
      for (int q = 0; q < 4; ++q) gv[q] = gs[row * 520 + q * 128 + u];
      #pragma unroll
      for (int q = 0; q < 4; ++q) {
        unsigned pu = __hip_atomic_load(
            (unsigned*)wsm + RP2 + (size_t)s8 * 131072 + (size_t)(r0 + row) * 512 + q * 128 + u,
            __ATOMIC_RELAXED, __HIP_MEMORY_SCOPE_AGENT);
        gv[q] += __builtin_bit_cast(float, pu);
      }
      const float xr = xs[row];
      #pragma unroll
      for (int q = 0; q < 4; ++q) gv[q] += fmaf(xw4[q], xr, bs4[q]);
      float& cref = rr ? cst1 : cst0;
      const float c = sigmoidf_(gv[1]) * cref + sigmoidf_(gv[0]) * tanhf(gv[2]);
      cref = c;
      const float h = sigmoidf_(gv[3]) * tanhf(c);
      const _Float16 hhi = (_Float16)h;
      const _Float16 hlo = (_Float16)((h - (float)hhi) * LO_SCALE);
      ah2[row * 136 + u] = hhi;
      al2[row * 136 + u] = hlo;
      const unsigned pk = (unsigned)__builtin_bit_cast(unsigned short, hhi)
                        | ((unsigned)__builtin_bit_cast(unsigned short, hlo) << 16);
      __hip_atomic_store(
          (unsigned*)wsm + RH2P + (size_t)s8 * 32768 + (size_t)(r0 + row) * 128 + u,
          pk, __ATOMIC_RELAXED, __HIP_MEMORY_SCOPE_AGENT);
    }
    __syncthreads();

    // ---- pA MFMA: Wih3a * h1(t) -> RPA ----
    ZACC4(accA); ZACC4(accB);
    #pragma unroll
    for (int kt = 0; kt < 4; ++kt) {
      const int k0 = kt * 32 + quad * 8;
      const v8h ahf = *(const v8h*)&ah1i[m * 136 + k0];
      const v8h alf = *(const v8h*)&al1i[m * 136 + k0];
      #pragma unroll
      for (int ntl = 0; ntl < 4; ++ntl) {
        MFMA_SPLIT(accA[ntl], accB[ntl], ahf, alf, bhi[1][kt][ntl], blo[1][kt][ntl]);
      }
    }
    if (quad < 2) {
      #pragma unroll
      for (int ntl = 0; ntl < 4; ++ntl) {
        const int c0 = (wv * 4 + ntl) * 16 + m;
        #pragma unroll
        for (int r = 0; r < 4; ++r) {
          const float pv = fmaf(LO_INV, accB[ntl][r], accA[ntl][r]);
          __hip_atomic_store(
              (unsigned*)wsm + RPA + (size_t)s8 * 131072 + (size_t)(r0 + quad * 4 + r) * 512 + c0,
              __builtin_bit_cast(unsigned, pv),
              __ATOMIC_RELAXED, __HIP_MEMORY_SCOPE_AGENT);
        }
      }
    }
    __syncthreads();
    if (tid == 0)
      __hip_atomic_fetch_add(FW2, 1u, __ATOMIC_RELAXED, __HIP_MEMORY_SCOPE_AGENT);
  }
}

// ---------------------------------------------------------------------------
// W3: pB + c3-core + head. Planes 4 (Wih3b), 5 (Whh3).
__device__ void stage_w3(float* __restrict__ wsm, char* SB, int g,
                         float* __restrict__ out) {
  const int tid = threadIdx.x;
  const int lane = tid & 63, wv = tid >> 6;
  const int m = lane & 15, quad = lane >> 4;
  const int r0 = g * 8;

  float*    gs   = (float*)SB;                 // [8][520]
  _Float16* ah3  = (_Float16*)(SB + 16640);
  _Float16* al3  = (_Float16*)(SB + 20992);
  _Float16* ah2i = (_Float16*)(SB + 25344);
  _Float16* al2i = (_Float16*)(SB + 29696);
  float*    hin  = (float*)(SB + 34048);       // [3][8][128] fp32
  float*    wl   = (float*)(SB + 46336);       // [512]
  float*    obuf = (float*)(SB + 48384);       // [8][32]
  float*    xv   = (float*)(SB + 49408);       // [8]

  unsigned* flagb = (unsigned*)wsm + FLAGS;
  unsigned* FW2 = flagb + (size_t)(1 * 32 + g) * 32;
  unsigned* FH  = flagb + (size_t)(2 * 32 + g) * 32;
  unsigned cw2 = 0;

  uint4 bhi[2][4][4], blo[2][4][4];
  #pragma unroll
  for (int p = 0; p < 2; ++p)
    #pragma unroll
    for (int kt = 0; kt < 4; ++kt)
      #pragma unroll
      for (int ntl = 0; ntl < 4; ++ntl) {
        const int di = ((((4 + p) * 4 + kt) * 32 + (wv * 4 + ntl)) * 64 + lane) * 4;
        bhi[p][kt][ntl] = *(const uint4*)((const unsigned*)wsm + BWHI + di);
        blo[p][kt][ntl] = *(const uint4*)((const unsigned*)wsm + BWLO + di);
      }
  const int row0 = tid >> 7, u = tid & 127;
  float xw4[4], bs4[4];
  #pragma unroll
  for (int q = 0; q < 4; ++q) {
    xw4[q] = wsm[SCAL + 2 * 512 + q * 128 + u];
    bs4[q] = wsm[SCAL + 1536 + 2 * 512 + q * 128 + u];
  }
  for (int i = tid; i < 1088; i += 512) {
    ((unsigned*)ah3)[i] = 0u;  ((unsigned*)al3)[i] = 0u;
    ((unsigned*)ah2i)[i] = 0u; ((unsigned*)al2i)[i] = 0u;
  }
  wl[tid] = wsm[WLIN + tid];
  if (tid < 8) xv[tid] = wsm[XT + r0 + tid];
  float cst0 = 0.f, cst1 = 0.f;
  __syncthreads();

  const int hrow = tid >> 6;   // head row

  for (int t = 0; t < TT; ++t) {
    if (tid == 0) wait_c(FW2, (unsigned)(t + 1), cw2);
    __syncthreads();
    const int s8 = t & 7;

    // stage packed h2(t) (-> MFMA frags + fp32) and h1(t) (-> fp32 for head)
    for (int i = tid; i < 1024; i += 512) {
      const int row = i >> 7, uu = i & 127;
      unsigned v2 = __hip_atomic_load(
          (unsigned*)wsm + RH2P + (size_t)s8 * 32768 + (size_t)(r0 + row) * 128 + uu,
          __ATOMIC_RELAXED, __HIP_MEMORY_SCOPE_AGENT);
      const _Float16 h2h = __builtin_bit_cast(_Float16, (unsigned short)(v2 & 0xffffu));
      const _Float16 h2l = __builtin_bit_cast(_Float16, (unsigned short)(v2 >> 16));
      ah2i[row * 136 + uu] = h2h;
      al2i[row * 136 + uu] = h2l;
      hin[(8 + row) * 128 + uu] = fmaf(LO_INV, (float)h2l, (float)h2h);
      unsigned v1 = __hip_atomic_load(
          (unsigned*)wsm + RH1P + (size_t)s8 * 32768 + (size_t)(r0 + row) * 128 + uu,
          __ATOMIC_RELAXED, __HIP_MEMORY_SCOPE_AGENT);
      const _Float16 h1h = __builtin_bit_cast(_Float16, (unsigned short)(v1 & 0xffffu));
      const _Float16 h1l = __builtin_bit_cast(_Float16, (unsigned short)(v1 >> 16));
      hin[row * 128 + uu] = fmaf(LO_INV, (float)h1l, (float)h1h);
    }
    __syncthreads();

    // ---- c3 MFMA: Wih3b*h2 + Whh3*h3own ----
    v4f accA[4], accB[4];
    ZACC4(accA); ZACC4(accB);
    #pragma unroll
    for (int kt = 0; kt < 4; ++kt) {
      const int k0 = kt * 32 + quad * 8;
      const v8h ahf = *(const v8h*)&ah2i[m * 136 + k0];
      const v8h alf = *(const v8h*)&al2i[m * 136 + k0];
      #pragma unroll
      for (int ntl = 0; ntl < 4; ++ntl) {
        MFMA_SPLIT(accA[ntl], accB[ntl], ahf, alf, bhi[0][kt][ntl], blo[0][kt][ntl]);
      }
    }
    #pragma unroll
    for (int kt = 0; kt < 4; ++kt) {
      const int k0 = kt * 32 + quad * 8;
      const v8h ahf = *(const v8h*)&ah3[m * 136 + k0];
      const v8h alf = *(const v8h*)&al3[m * 136 + k0];
      #pragma unroll
      for (int ntl = 0; ntl < 4; ++ntl) {
        MFMA_SPLIT(accA[ntl], accB[ntl], ahf, alf, bhi[1][kt][ntl], blo[1][kt][ntl]);
      }
    }
    if (quad < 2) {
      #pragma unroll
      for (int ntl = 0; ntl < 4; ++ntl) {
        const int c0 = (wv * 4 + ntl) * 16 + m;
        #pragma unroll
        for (int r = 0; r < 4; ++r)
          gs[(quad * 4 + r) * 520 + c0] = fmaf(LO_INV, accB[ntl][r], accA[ntl][r]);
      }
    }
    __syncthreads();

    // ---- epi3: + pA ring + x-term; h3 -> LDS frags + hin fp32 ----
    #pragma unroll
    for (int rr = 0; rr < 2; ++rr) {
      const int row = row0 + rr * 4;
      float gv[4];
      #pragma unroll
      for (int q = 0; q < 4; ++q) gv[q] = gs[row * 520 + q * 128 + u];
      #pragma unroll
      for (int q = 0; q < 4; ++q) {
        unsigned pu = __hip_atomic_load(
            (unsigned*)wsm + RPA + (size_t)s8 * 131072 + (size_t)(r0 + row) * 512 + q * 128 + u,
            __ATOMIC_RELAXED, __HIP_MEMORY_SCOPE_AGENT);
        gv[q] += __builtin_bit_cast(float, pu);
      }
      const float xr = xv[row];
      #pragma unroll
      for (int q = 0; q < 4; ++q) gv[q] += fmaf(xw4[q], xr, bs4[q]);
      float& cref = rr ? cst1 : cst0;
      const float c = sigmoidf_(gv[1]) * cref + sigmoidf_(gv[0]) * tanhf(gv[2]);
      cref = c;
      const float h = sigmoidf_(gv[3]) * tanhf(c);
      const _Float16 hhi = (_Float16)h;
      const _Float16 hlo = (_Float16)((h - (float)hhi) * LO_SCALE);
      ah3[row * 136 + u] = hhi;
      al3[row * 136 + u] = hlo;
      hin[(16 + row) * 128 + u] = h;
    }
    __syncthreads();

    // ---- head: o = Wlin.[x,h1,h2,h3] + b ----
    {
      float s = 0.f;
      #pragma unroll
      for (int q = 0; q < 6; ++q) {
        const int j = lane + 64 * q;          // 0..383
        const int si = j >> 7, uu = j & 127;
        s = fmaf(wl[1 + j], hin[(si * 8 + hrow) * 128 + uu], s);
      }
      #pragma unroll
      for (int off = 32; off > 0; off >>= 1) s += __shfl_down(s, off, 64);
      if (lane == 0) {
        const float o = s + fmaf(wl[0], xv[hrow], wl[385]);
        obuf[hrow * 32 + (t & 31)] = o;
        __hip_atomic_store((unsigned*)wsm + RO + (size_t)(t & 15) * 256 + r0 + hrow,
                           __builtin_bit_cast(unsigned, o),
                           __ATOMIC_RELAXED, __HIP_MEMORY_SCOPE_AGENT);
        xv[hrow] = (t + 1 < TSEQ) ? wsm[XT + (size_t)(t + 1) * 256 + r0 + hrow] : o;
      }
    }
    __syncthreads();
    if (tid == 0)
      __hip_atomic_fetch_add(FH, 1u, __ATOMIC_RELAXED, __HIP_MEMORY_SCOPE_AGENT);

    if ((t & 31) == 31) {
      const int tb = t - 31;
      if (tid < 256) {
        const int a = tid >> 5, mm = tid & 31;
        out[(size_t)(r0 + a) * TT + tb + mm] = obuf[a * 32 + mm];
      }
    }
  }
}

// ---------------------------------------------------------------------------
__global__ __launch_bounds__(512, 2)
void lstm_kernel(float* __restrict__ wsm, float* __restrict__ out) {
  __shared__ __align__(16) char SB[49664];
  const int bid = blockIdx.x;
  if (bid < 32)      stage_w1(wsm, SB, bid);
  else if (bid < 64) stage_w2(wsm, SB, bid - 32);
  else               stage_w3(wsm, SB, bid - 64, out);
}

// ---------------------------------------------------------------------------
extern "C" void kernel_launch(void* const* d_in, const int* in_sizes, int n_in,
                              void* d_out, int out_size, void* d_ws, size_t ws_size,
                              hipStream_t stream) {
  const float* x    = (const float*)d_in[0];
  const float* Wih1 = (const float*)d_in[1];
  const float* Whh1 = (const float*)d_in[2];
  const float* bih1 = (const float*)d_in[3];
  const float* bhh1 = (const float*)d_in[4];
  const float* Wih2 = (const float*)d_in[5];
  const float* Whh2 = (const float*)d_in[6];
  const float* bih2 = (const float*)d_in[7];
  const float* bhh2 = (const float*)d_in[8];
  const float* Wih3 = (const float*)d_in[9];
  const float* Whh3 = (const float*)d_in[10];
  const float* bih3 = (const float*)d_in[11];
  const float* bhh3 = (const float*)d_in[12];
  const float* Wlin = (const float*)d_in[13];
  const float* blin = (const float*)d_in[14];
  float* ws  = (float*)d_ws;
  float* out = (float*)d_out;

  prep_kernel<<<PREP_T / 256, 256, 0, stream>>>(
      x, Wih1, Whh1, bih1, bhh1, Wih2, Whh2, bih2, bhh2,
      Wih3, Whh3, bih3, bhh3, Wlin, blin, ws);
  lstm_kernel<<<96, 512, 0, stream>>>(ws, out);
}